// Round 3
// baseline (431.905 us; speedup 1.0000x reference)
//
#include <hip/hip_runtime.h>

#define SROW 132   // padded fp32 row stride for S (balanced banks for all access patterns)

typedef _Float16 half8 __attribute__((ext_vector_type(8)));
typedef float f32x4 __attribute__((ext_vector_type(4)));

// MFMA quadratic-form + softmax, v2.
// Changes vs v1 (429 us): A-fragments hoisted to registers (built once, not
// per chunk); sigma prefetch in 16 NAMED float regs (no array, no lambda ->
// no scratch risk); single-buffer Bp (16 KB) -> LDS 50.4 KB -> 3 blocks/CU
// (was 2) so cross-block TLP covers the per-chunk vmcnt/barrier drains.

__global__ __launch_bounds__(256, 3)
void quadform_softmax(const float* __restrict__ color,
                      const float* __restrict__ mew,
                      const float* __restrict__ sigma,
                      float* __restrict__ out) {
  __shared__ __align__(16) float s_all[4 * 16 * SROW];   // 33792 B, per-wave S (fp32, epilogue + A-build)
  __shared__ __align__(16) _Float16 Bp[2][8][64][8];     // 16384 B: [hi/lo][tile][slot][j]
  __shared__ float scores_lds[64];

  const int tid  = threadIdx.x;
  const int wv   = tid >> 6;
  const int lane = tid & 63;
  const int m    = blockIdx.x;

  float* sw = &s_all[wv * (16 * SROW)];
  const float* sg  = sigma + (size_t)m * 16384;
  const float* sgh = sg + wv * (8 * 128);   // this wave's 8-row k-subgroup of each 32-row chunk

  // ---- sigma chunk prefetch registers (named -> guaranteed VGPRs) ----
  float p0,p1,p2,p3,p4,p5,p6,p7,p8,p9,p10,p11,p12,p13,p14,p15;

#define SIG_LOAD(CH) do {                                               \
    const float* gp = sgh + (CH) * (32 * 128);                          \
    p0  = gp[0*128 + lane];       p1  = gp[1*128 + lane];               \
    p2  = gp[2*128 + lane];       p3  = gp[3*128 + lane];               \
    p4  = gp[4*128 + lane];       p5  = gp[5*128 + lane];               \
    p6  = gp[6*128 + lane];       p7  = gp[7*128 + lane];               \
    p8  = gp[0*128 + 64 + lane];  p9  = gp[1*128 + 64 + lane];          \
    p10 = gp[2*128 + 64 + lane];  p11 = gp[3*128 + 64 + lane];          \
    p12 = gp[4*128 + 64 + lane];  p13 = gp[5*128 + 64 + lane];          \
    p14 = gp[6*128 + 64 + lane];  p15 = gp[7*128 + 64 + lane];          \
  } while (0)

#define CV(H, L, I, X) do { _Float16 t_ = (_Float16)(X);                \
    H[I] = t_; L[I] = (_Float16)((X) - (float)t_); } while (0)

  // convert p0..p15 -> f16 hi/lo planes, write B-fragment slots
  // value = Sigma[kc + 8*wv + j][16*tile + r]; slot = wv*16 + r
#define SIG_WRITE() do {                                                \
    half8 hi0, lo0, hi1, lo1;                                           \
    CV(hi0, lo0, 0, p0);  CV(hi0, lo0, 1, p1);                          \
    CV(hi0, lo0, 2, p2);  CV(hi0, lo0, 3, p3);                          \
    CV(hi0, lo0, 4, p4);  CV(hi0, lo0, 5, p5);                          \
    CV(hi0, lo0, 6, p6);  CV(hi0, lo0, 7, p7);                          \
    CV(hi1, lo1, 0, p8);  CV(hi1, lo1, 1, p9);                          \
    CV(hi1, lo1, 2, p10); CV(hi1, lo1, 3, p11);                         \
    CV(hi1, lo1, 4, p12); CV(hi1, lo1, 5, p13);                         \
    CV(hi1, lo1, 6, p14); CV(hi1, lo1, 7, p15);                         \
    const int t0_ = lane >> 4, slot_ = wv * 16 + (lane & 15);           \
    *reinterpret_cast<half8*>(&Bp[0][t0_    ][slot_][0]) = hi0;         \
    *reinterpret_cast<half8*>(&Bp[1][t0_    ][slot_][0]) = lo0;         \
    *reinterpret_cast<half8*>(&Bp[0][t0_ + 4][slot_][0]) = hi1;         \
    *reinterpret_cast<half8*>(&Bp[1][t0_ + 4][slot_][0]) = lo1;         \
  } while (0)

  // issue chunk-0 sigma loads first; latency hides under all staging below
  SIG_LOAD(0);

  // ---- stage shifted rows [16wv,16wv+16) into this wave's private S ----
  {
    const int hh = lane >> 5;
    const int q  = lane & 31;
    const float4* c4 = reinterpret_cast<const float4*>(color + (size_t)m * 8192)
                       + (size_t)(16 * wv) * 32;
    const float4 mw = reinterpret_cast<const float4*>(mew + (size_t)m * 128)[q];
#pragma unroll
    for (int r = 0; r < 8; ++r) {
      const int row = hh + 2 * r;
      float4 v = c4[row * 32 + q];
      v.x -= mw.x; v.y -= mw.y; v.z -= mw.z; v.w -= mw.w;
      *reinterpret_cast<float4*>(&sw[row * SROW + 4 * q]) = v;
    }
  }
  // wave-local write->read: compiler lgkmcnt ordering suffices, no barrier.

  // ---- build all 4 chunks' A fragments ONCE into registers ----
  const int hl = lane >> 4;   // k-group
  const int rl = lane & 15;   // A row within wave-tile
  half8 aH0, aL0, aH1, aL1, aH2, aL2, aH3, aL3;

#define A_BUILD(Q, AH, AL) do {                                         \
    const float* sa_ = &sw[rl * SROW + (Q) * 32 + 8 * hl];              \
    float4 x0_ = *reinterpret_cast<const float4*>(sa_);                 \
    float4 x1_ = *reinterpret_cast<const float4*>(sa_ + 4);             \
    CV(AH, AL, 0, x0_.x); CV(AH, AL, 1, x0_.y);                         \
    CV(AH, AL, 2, x0_.z); CV(AH, AL, 3, x0_.w);                         \
    CV(AH, AL, 4, x1_.x); CV(AH, AL, 5, x1_.y);                         \
    CV(AH, AL, 6, x1_.z); CV(AH, AL, 7, x1_.w);                         \
  } while (0)

  A_BUILD(0, aH0, aL0);
  A_BUILD(1, aH1, aL1);
  A_BUILD(2, aH2, aL2);
  A_BUILD(3, aH3, aL3);

  // chunk 0 into Bp (waits on SIG_LOAD(0) vmcnt), then publish
  SIG_WRITE();
  __syncthreads();

  f32x4 acc[8];
#pragma unroll
  for (int t = 0; t < 8; ++t) acc[t] = (f32x4){0.f, 0.f, 0.f, 0.f};

#define MT(T, AH, AL) do {                                                    \
    half8 bh_ = *reinterpret_cast<const half8*>(&Bp[0][T][lane][0]);          \
    half8 bl_ = *reinterpret_cast<const half8*>(&Bp[1][T][lane][0]);          \
    acc[T] = __builtin_amdgcn_mfma_f32_16x16x32_f16(AH, bh_, acc[T], 0,0,0);  \
    acc[T] = __builtin_amdgcn_mfma_f32_16x16x32_f16(AH, bl_, acc[T], 0,0,0);  \
    acc[T] = __builtin_amdgcn_mfma_f32_16x16x32_f16(AL, bh_, acc[T], 0,0,0);  \
  } while (0)

#define MFMA_CHUNK(AH, AL) do {                                         \
    MT(0, AH, AL); MT(1, AH, AL); MT(2, AH, AL); MT(3, AH, AL);         \
    MT(4, AH, AL); MT(5, AH, AL); MT(6, AH, AL); MT(7, AH, AL);         \
  } while (0)

  // ---- 4 chunks, single Bp buffer, prefetch in registers ----
  SIG_LOAD(1);
  MFMA_CHUNK(aH0, aL0);
  __syncthreads();            // all waves done reading Bp chunk 0
  SIG_WRITE();                // waits vmcnt for chunk 1 (issued before MFMA)
  __syncthreads();            // Bp chunk 1 published

  SIG_LOAD(2);
  MFMA_CHUNK(aH1, aL1);
  __syncthreads();
  SIG_WRITE();
  __syncthreads();

  SIG_LOAD(3);
  MFMA_CHUNK(aH2, aL2);
  __syncthreads();
  SIG_WRITE();
  __syncthreads();

  MFMA_CHUNK(aH3, aL3);

  // ---- epilogue: score[p] = -sum_col T[p,col] * S[p,col] ----
  // D layout (verified): row = 4*(lane>>4)+reg, col = 16*tile + (lane&15)
  float part[4] = {0.f, 0.f, 0.f, 0.f};
#pragma unroll
  for (int t = 0; t < 8; ++t) {
#pragma unroll
    for (int r = 0; r < 4; ++r) {
      float sv = sw[(4 * hl + r) * SROW + 16 * t + rl];
      part[r] = fmaf(acc[t][r], sv, part[r]);
    }
  }
#pragma unroll
  for (int r = 0; r < 4; ++r) {
    part[r] += __shfl_xor(part[r], 1, 64);
    part[r] += __shfl_xor(part[r], 2, 64);
    part[r] += __shfl_xor(part[r], 4, 64);
    part[r] += __shfl_xor(part[r], 8, 64);
  }
  if (rl == 0) {
#pragma unroll
    for (int r = 0; r < 4; ++r)
      scores_lds[wv * 16 + 4 * hl + r] = -part[r];
  }
  __syncthreads();

  // ---- softmax over the 64 scores (single wave) ----
  if (tid < 64) {
    float sc = scores_lds[tid];
    float mx = sc;
#pragma unroll
    for (int off = 1; off < 64; off <<= 1) mx = fmaxf(mx, __shfl_xor(mx, off, 64));
    float e = __expf(sc - mx);
    float s = e;
#pragma unroll
    for (int off = 1; off < 64; off <<= 1) s += __shfl_xor(s, off, 64);
    out[(size_t)m * 64 + tid] = e / s;
  }
}

extern "C" void kernel_launch(void* const* d_in, const int* in_sizes, int n_in,
                              void* d_out, int out_size, void* d_ws, size_t ws_size,
                              hipStream_t stream) {
  const float* color = (const float*)d_in[0];   // (M,64,128) fp32
  const float* mew   = (const float*)d_in[1];   // (M,128)    fp32
  const float* sigma = (const float*)d_in[2];   // (M,128,128) fp32
  float* out = (float*)d_out;                   // (M,64) fp32
  const int M = in_sizes[1] / 128;
  quadform_softmax<<<M, 256, 0, stream>>>(color, mew, sigma, out);
}